// Round 1
// baseline (610.005 us; speedup 1.0000x reference)
//
#include <hip/hip_runtime.h>
#include <math.h>

// Problem constants (B=4, N=2048, C=81)
#define NPROP 2048
#define NIMG 4
#define NCLS 81
#define REGW 648          // C*8
#define SCORE_THRESH 0.05f
#define NMS_T 0.5f
#define DETS 100
#define XC 1023.0f        // IMG_W - 1
#define YC 799.0f         // IMG_H - 1
#define BBOX_CLIP 4.135166556742356f  // log(1000/16)

// ---------------------------------------------------------------------------
// K1: per-row softmax-argmax + box decode (argmax class only) + clip.
// One wave (64 lanes) per row; 4 rows per 256-thread block.
// ---------------------------------------------------------------------------
__device__ __forceinline__ void decode_clip(float r0, float r1, float r2, float r3,
                                            float px1, float py1, float px2, float py2,
                                            float* __restrict__ o) {
  float w  = px2 - px1 + 1.0f;
  float h  = py2 - py1 + 1.0f;
  float cx = px1 + 0.5f * w;
  float cy = py1 + 0.5f * h;
  float dx = r0 / 10.0f;
  float dy = r1 / 10.0f;
  float dw = fminf(r2 / 5.0f, BBOX_CLIP);
  float dh = fminf(r3 / 5.0f, BBOX_CLIP);
  float pcx = dx * w + cx;
  float pcy = dy * h + cy;
  float pw = expf(dw) * w;
  float ph = expf(dh) * h;
  float x1 = pcx - 0.5f * pw;
  float y1 = pcy - 0.5f * ph;
  float x2 = pcx + 0.5f * pw - 1.0f;
  float y2 = pcy + 0.5f * ph - 1.0f;
  o[0] = fminf(fmaxf(x1, 0.0f), XC);
  o[1] = fminf(fmaxf(y1, 0.0f), YC);
  o[2] = fminf(fmaxf(x2, 0.0f), XC);
  o[3] = fminf(fmaxf(y2, 0.0f), YC);
}

__global__ __launch_bounds__(256) void decode_kernel(
    const float* __restrict__ logits, const float* __restrict__ reg,
    const float* __restrict__ lp, const float* __restrict__ rp,
    float* __restrict__ scores, int* __restrict__ valid,
    float* __restrict__ lbox, float* __restrict__ rbox) {
  int row  = blockIdx.x * 4 + (threadIdx.x >> 6);
  int lane = threadIdx.x & 63;
  const float* lr = logits + (size_t)row * NCLS;
  float a = lr[lane];                                       // classes 0..63
  float b = (lane < NCLS - 64) ? lr[lane + 64] : -INFINITY; // classes 64..80
  // local best with first-index tie-break (a's index < b's index)
  float v; int ci;
  if (b > a) { v = b; ci = lane + 64; } else { v = a; ci = lane; }
  // wave argmax (max value, min index on ties) == jnp.argmax semantics
  for (int o = 32; o; o >>= 1) {
    float ov = __shfl_xor(v, o);
    int   oc = __shfl_xor(ci, o);
    if (ov > v || (ov == v && oc < ci)) { v = ov; ci = oc; }
  }
  // sum of exp(x - max); softmax at argmax = 1/sum (numerator exp(0)==1)
  float e = expf(a - v) + ((lane < NCLS - 64) ? expf(b - v) : 0.0f);
  for (int o = 32; o; o >>= 1) e += __shfl_xor(e, o);
  if (lane == 0) {
    float score = 1.0f / e;
    scores[row] = score;
    valid[row]  = (ci >= 1 && score > SCORE_THRESH) ? 1 : 0;
    const float* r = reg + (size_t)row * REGW + ci * 8;
    const float* L = lp + row * 4;
    const float* R = rp + row * 4;
    decode_clip(r[0], r[1], r[2], r[3], L[0], L[1], L[2], L[3], lbox + (size_t)row * 4);
    decode_clip(r[4], r[5], r[6], r[7], R[0], R[1], R[2], R[3], rbox + (size_t)row * 4);
  }
}

// ---------------------------------------------------------------------------
// K2: per (image, side): bitonic sort by (-score, idx) then chunked greedy NMS.
// grid = 8 blocks (b = blk>>1, side = blk&1), 1024 threads.
// ---------------------------------------------------------------------------
__global__ __launch_bounds__(1024) void sort_nms_kernel(
    const float* __restrict__ scores, const int* __restrict__ valid,
    const float* __restrict__ lbox, const float* __restrict__ rbox,
    int* __restrict__ sidx, int* __restrict__ keepS) {
  __shared__ unsigned long long key[NPROP]; // 16 KB
  __shared__ float4 bx[NPROP];              // 32 KB (sorted boxes)
  __shared__ float  areas[NPROP];           // 8 KB
  __shared__ unsigned char keep[NPROP];     // 2 KB
  __shared__ float cb[64][5];               // chunk survivors (box + area)
  __shared__ int ccnt;
  __shared__ int nv_s;

  int b = blockIdx.x >> 1, side = blockIdx.x & 1;
  int tid = threadIdx.x;
  const float* sc = scores + b * NPROP;
  const int*   vd = valid  + b * NPROP;
  const float4* boxes = (const float4*)(side == 0 ? lbox : rbox) + b * NPROP;

  if (tid == 0) nv_s = 0;
  __syncthreads();
  int lc = 0;
  for (int p = tid; p < NPROP; p += 1024) {
    int vl = vd[p];
    lc += vl;
    float s = vl ? sc[p] : -INFINITY;
    unsigned u = __float_as_uint(s);
    u = (u & 0x80000000u) ? ~u : (u | 0x80000000u);   // total-order map
    key[p] = ((unsigned long long)(~u) << 32) | (unsigned)p; // asc == desc score, idx asc ties
  }
  atomicAdd(&nv_s, lc);

  // bitonic ascending sort of 2048 u64 keys, 1024 comparators/stage
  for (int size = 2; size <= NPROP; size <<= 1) {
    for (int stride = size >> 1; stride; stride >>= 1) {
      __syncthreads();
      int i = ((tid & ~(stride - 1)) << 1) | (tid & (stride - 1));
      int j = i + stride;
      unsigned long long ka = key[i], kb = key[j];
      bool up = ((i & size) == 0);
      if ((ka > kb) == up) { key[i] = kb; key[j] = ka; }
    }
  }
  __syncthreads();

  for (int p = tid; p < NPROP; p += 1024) {
    int oi = (int)(key[p] & 0xffffffffu);
    if (side == 0) sidx[b * NPROP + p] = oi;   // both sides sort identically
    float4 v = boxes[oi];
    bx[p] = v;
    areas[p] = fmaxf(v.z - v.x + 1.0f, 0.0f) * fmaxf(v.w - v.y + 1.0f, 0.0f);
    keep[p] = 1;
  }
  __syncthreads();

  int nv = nv_s;  // only valid boxes can suppress / need keep bits
  for (int base = 0; base < nv; base += 64) {
    int lim = min(base + 64, nv);
    if (tid < 64) {  // wave 0: resolve intra-chunk greedy
      int p = base + tid;                       // p <= 2047 always
      bool alive = (p < lim) && keep[p];
      float4 mb = bx[p];
      float  ar = areas[p];
      unsigned long long aliveM = __ballot(alive);
      unsigned long long processed = 0ull;
      for (;;) {
        unsigned long long m = aliveM & ~processed;
        if (m == 0ull) break;
        int i = __ffsll((unsigned long long)m) - 1;   // next surviving box
        processed |= (1ull << i);
        float ox1 = __shfl(mb.x, i), oy1 = __shfl(mb.y, i);
        float ox2 = __shfl(mb.z, i), oy2 = __shfl(mb.w, i);
        float oar = __shfl(ar, i);
        if (alive && tid > i) {
          float ix1 = fmaxf(mb.x, ox1), iy1 = fmaxf(mb.y, oy1);
          float ix2 = fminf(mb.z, ox2), iy2 = fminf(mb.w, oy2);
          float iw = fmaxf(ix2 - ix1 + 1.0f, 0.0f);
          float ih = fmaxf(iy2 - iy1 + 1.0f, 0.0f);
          float inter = iw * ih;
          float iou = inter / fmaxf(ar + oar - inter, 1e-6f);
          if (iou > NMS_T) alive = false;
        }
        aliveM = __ballot(alive);
      }
      if (p < lim) keep[p] = alive ? 1 : 0;
      if (alive) {  // compact survivors for the broadcast phase
        int pos = __popcll(aliveM & ((1ull << tid) - 1ull));
        cb[pos][0] = mb.x; cb[pos][1] = mb.y; cb[pos][2] = mb.z; cb[pos][3] = mb.w;
        cb[pos][4] = ar;
      }
      if (tid == 0) ccnt = __popcll(aliveM);
    }
    __syncthreads();
    int cnt = ccnt;
    if (cnt > 0) {  // chunk survivors suppress all later boxes, in parallel
      for (int p = lim + tid; p < nv; p += 1024) {
        if (!keep[p]) continue;
        float4 mb = bx[p];
        float  ar = areas[p];
        bool al = true;
        for (int q = 0; q < cnt; ++q) {
          float ix1 = fmaxf(mb.x, cb[q][0]), iy1 = fmaxf(mb.y, cb[q][1]);
          float ix2 = fminf(mb.z, cb[q][2]), iy2 = fminf(mb.w, cb[q][3]);
          float iw = fmaxf(ix2 - ix1 + 1.0f, 0.0f);
          float ih = fmaxf(iy2 - iy1 + 1.0f, 0.0f);
          float inter = iw * ih;
          float iou = inter / fmaxf(ar + cb[q][4] - inter, 1e-6f);
          if (iou > NMS_T) { al = false; break; }
        }
        if (!al) keep[p] = 0;
      }
    }
    __syncthreads();
  }

  for (int p = tid; p < NPROP; p += 1024)
    keepS[(side * NIMG + b) * NPROP + p] = keep[p];
}

// ---------------------------------------------------------------------------
// K3: per image: combine keeps, top-100 threshold via prefix scan, write output.
// grid = 4 blocks, 1024 threads (2 sorted positions per thread).
// ---------------------------------------------------------------------------
__global__ __launch_bounds__(1024) void finalize_kernel(
    const float* __restrict__ scores, const int* __restrict__ valid,
    const float* __restrict__ lbox, const float* __restrict__ rbox,
    const int* __restrict__ sidx, const int* __restrict__ keepS,
    float* __restrict__ out) {
  __shared__ int pc[1024];
  __shared__ float kth_s;
  int b = blockIdx.x;
  int tid = threadIdx.x;
  const int* si = sidx + b * NPROP;
  const int* kL = keepS + (0 * NIMG + b) * NPROP;
  const int* kR = keepS + (1 * NIMG + b) * NPROP;
  const float* sc = scores + b * NPROP;
  const int*   vd = valid  + b * NPROP;

  int p0 = tid * 2, p1 = p0 + 1;
  int o0 = si[p0], o1 = si[p1];
  int k0 = (kL[p0] && kR[p0] && vd[o0]) ? 1 : 0;
  int k1 = (kL[p1] && kR[p1] && vd[o1]) ? 1 : 0;
  if (tid == 0) kth_s = -INFINITY;
  pc[tid] = k0 + k1;
  __syncthreads();
  // Hillis-Steele inclusive scan over 1024 per-thread counts
  for (int ofs = 1; ofs < 1024; ofs <<= 1) {
    int add = (tid >= ofs) ? pc[tid - ofs] : 0;
    __syncthreads();
    pc[tid] += add;
    __syncthreads();
  }
  int incl  = pc[tid];
  int total = pc[1023];
  int ex    = incl - (k0 + k1);  // kept count before p0
  if (total >= DETS) {           // score of the 100th kept box (sorted desc)
    if (k0 && ex == DETS - 1)      kth_s = sc[o0];
    if (k1 && ex + k0 == DETS - 1) kth_s = sc[o1];
  }
  __syncthreads();
  float kth = kth_s;  // -inf if fewer than 100 kept -> keep all (ms >= -inf)

  float* ob = out + (size_t)b * NPROP * 9;
  for (int x = tid; x < NPROP * 9; x += 1024) ob[x] = 0.0f;
  __syncthreads();

#pragma unroll
  for (int q = 0; q < 2; ++q) {
    int kk = q ? k1 : k0;
    int oi = q ? o1 : o0;
    if (kk) {
      float s = sc[oi];
      if (s >= kth) {   // reproduces top_k tie semantics (ms >= kth)
        const float* L = lbox + (size_t)(b * NPROP + oi) * 4;
        const float* R = rbox + (size_t)(b * NPROP + oi) * 4;
        float* orow = ob + (size_t)oi * 9;
        orow[0] = L[0]; orow[1] = L[1]; orow[2] = L[2]; orow[3] = L[3];
        orow[4] = R[0]; orow[5] = R[1]; orow[6] = R[2]; orow[7] = R[3];
        orow[8] = s;
      }
    }
  }
}

// ---------------------------------------------------------------------------
extern "C" void kernel_launch(void* const* d_in, const int* in_sizes, int n_in,
                              void* d_out, int out_size, void* d_ws, size_t ws_size,
                              hipStream_t stream) {
  const float* logits = (const float*)d_in[0];   // [8192, 81]
  const float* reg    = (const float*)d_in[1];   // [8192, 648]
  const float* lprop  = (const float*)d_in[2];   // [8192, 4]
  const float* rprop  = (const float*)d_in[3];   // [8192, 4]
  float* out = (float*)d_out;                    // [4, 2048, 9]

  // workspace layout (float slots); total ~426 KB
  float* wsf    = (float*)d_ws;
  float* scores = wsf;                  // 8192
  int*   valid  = (int*)(wsf + 8192);   // 8192
  float* lbox   = wsf + 16384;          // 8192*4 (16B aligned)
  float* rbox   = wsf + 49152;          // 8192*4
  int*   sidx   = (int*)(wsf + 81920);  // 4*2048
  int*   keepS  = (int*)(wsf + 90112);  // 2*4*2048

  decode_kernel  <<<NIMG * NPROP / 4, 256,  0, stream>>>(logits, reg, lprop, rprop,
                                                         scores, valid, lbox, rbox);
  sort_nms_kernel<<<2 * NIMG,         1024, 0, stream>>>(scores, valid, lbox, rbox,
                                                         sidx, keepS);
  finalize_kernel<<<NIMG,             1024, 0, stream>>>(scores, valid, lbox, rbox,
                                                         sidx, keepS, out);
}

// Round 2
// 475.412 us; speedup vs baseline: 1.2831x; 1.2831x over previous
//
#include <hip/hip_runtime.h>
#include <math.h>

// Problem constants (B=4, N=2048, C=81)
#define NPROP 2048
#define NIMG 4
#define NCLS 81
#define REGW 648          // C*8
#define SCORE_THRESH 0.05f
#define NMS_T 0.5f
#define DETS 100
#define XC 1023.0f        // IMG_W - 1
#define YC 799.0f         // IMG_H - 1
#define BBOX_CLIP 4.135166556742356f  // log(1000/16)

// ---------------------------------------------------------------------------
// K1: per-row softmax-argmax + box decode (argmax class only) + clip.
// One wave (64 lanes) per row; 4 rows per 256-thread block.
// ---------------------------------------------------------------------------
__device__ __forceinline__ void decode_clip(float r0, float r1, float r2, float r3,
                                            float px1, float py1, float px2, float py2,
                                            float* __restrict__ o) {
  float w  = px2 - px1 + 1.0f;
  float h  = py2 - py1 + 1.0f;
  float cx = px1 + 0.5f * w;
  float cy = py1 + 0.5f * h;
  float dx = r0 / 10.0f;
  float dy = r1 / 10.0f;
  float dw = fminf(r2 / 5.0f, BBOX_CLIP);
  float dh = fminf(r3 / 5.0f, BBOX_CLIP);
  float pcx = dx * w + cx;
  float pcy = dy * h + cy;
  float pw = expf(dw) * w;
  float ph = expf(dh) * h;
  float x1 = pcx - 0.5f * pw;
  float y1 = pcy - 0.5f * ph;
  float x2 = pcx + 0.5f * pw - 1.0f;
  float y2 = pcy + 0.5f * ph - 1.0f;
  o[0] = fminf(fmaxf(x1, 0.0f), XC);
  o[1] = fminf(fmaxf(y1, 0.0f), YC);
  o[2] = fminf(fmaxf(x2, 0.0f), XC);
  o[3] = fminf(fmaxf(y2, 0.0f), YC);
}

__global__ __launch_bounds__(256) void decode_kernel(
    const float* __restrict__ logits, const float* __restrict__ reg,
    const float* __restrict__ lp, const float* __restrict__ rp,
    float* __restrict__ scores, int* __restrict__ valid,
    float* __restrict__ lbox, float* __restrict__ rbox) {
  int row  = blockIdx.x * 4 + (threadIdx.x >> 6);
  int lane = threadIdx.x & 63;
  const float* lr = logits + (size_t)row * NCLS;
  float a = lr[lane];                                       // classes 0..63
  float b = (lane < NCLS - 64) ? lr[lane + 64] : -INFINITY; // classes 64..80
  float v; int ci;
  if (b > a) { v = b; ci = lane + 64; } else { v = a; ci = lane; }
  // wave argmax (max value, min index on ties) == jnp.argmax semantics
  for (int o = 32; o; o >>= 1) {
    float ov = __shfl_xor(v, o);
    int   oc = __shfl_xor(ci, o);
    if (ov > v || (ov == v && oc < ci)) { v = ov; ci = oc; }
  }
  // sum of exp(x - max); softmax at argmax = 1/sum (numerator exp(0)==1)
  float e = expf(a - v) + ((lane < NCLS - 64) ? expf(b - v) : 0.0f);
  for (int o = 32; o; o >>= 1) e += __shfl_xor(e, o);
  if (lane == 0) {
    float score = 1.0f / e;
    scores[row] = score;
    valid[row]  = (ci >= 1 && score > SCORE_THRESH) ? 1 : 0;
    const float* r = reg + (size_t)row * REGW + ci * 8;
    const float* L = lp + row * 4;
    const float* R = rp + row * 4;
    decode_clip(r[0], r[1], r[2], r[3], L[0], L[1], L[2], L[3], lbox + (size_t)row * 4);
    decode_clip(r[4], r[5], r[6], r[7], R[0], R[1], R[2], R[3], rbox + (size_t)row * 4);
  }
}

// ---------------------------------------------------------------------------
// K2: per (image, side): bitonic sort, then chunked greedy NMS where the
// intra-chunk greedy runs on a 32x32 bit matrix (built by wave-parallel
// ballots) with a single-thread unrolled scalar loop — no cross-lane ops in
// the serial dependent chain.
// grid = 8 blocks (b = blk>>1, side = blk&1), 1024 threads.
// ---------------------------------------------------------------------------
#define CH 32   // NMS chunk size

__global__ __launch_bounds__(1024) void sort_nms_kernel(
    const float* __restrict__ scores, const int* __restrict__ valid,
    const float* __restrict__ lbox, const float* __restrict__ rbox,
    int* __restrict__ sidx, int* __restrict__ keepS) {
  __shared__ unsigned long long key[NPROP]; // 16 KB
  __shared__ float4 bx[NPROP];              // 32 KB (sorted boxes)
  __shared__ float  areas[NPROP];           // 8 KB
  __shared__ unsigned keepbits[NPROP / 32]; // 256 B keep bitmask (sorted order)
  __shared__ unsigned rowmask[CH];          // 32x32 suppression bit matrix
  __shared__ float cb[CH][5];               // chunk survivors (box + area)
  __shared__ int ccnt;
  __shared__ int nv_s;

  int b = blockIdx.x >> 1, side = blockIdx.x & 1;
  int tid = threadIdx.x;
  const float* sc = scores + b * NPROP;
  const int*   vd = valid  + b * NPROP;
  const float4* boxes = (const float4*)(side == 0 ? lbox : rbox) + b * NPROP;

  if (tid == 0) nv_s = 0;
  __syncthreads();
  int lc = 0;
  for (int p = tid; p < NPROP; p += 1024) {
    int vl = vd[p];
    lc += vl;
    float s = vl ? sc[p] : -INFINITY;
    unsigned u = __float_as_uint(s);
    u = (u & 0x80000000u) ? ~u : (u | 0x80000000u);   // total-order map
    key[p] = ((unsigned long long)(~u) << 32) | (unsigned)p; // asc == desc score, idx asc ties
  }
  atomicAdd(&nv_s, lc);

  // bitonic ascending sort of 2048 u64 keys, 1024 comparators/stage
  for (int size = 2; size <= NPROP; size <<= 1) {
    for (int stride = size >> 1; stride; stride >>= 1) {
      __syncthreads();
      int i = ((tid & ~(stride - 1)) << 1) | (tid & (stride - 1));
      int j = i + stride;
      unsigned long long ka = key[i], kb = key[j];
      bool up = ((i & size) == 0);
      if ((ka > kb) == up) { key[i] = kb; key[j] = ka; }
    }
  }
  __syncthreads();

  for (int p = tid; p < NPROP; p += 1024) {
    int oi = (int)(key[p] & 0xffffffffu);
    if (side == 0) sidx[b * NPROP + p] = oi;   // both sides sort identically
    float4 v = boxes[oi];
    bx[p] = v;
    areas[p] = fmaxf(v.z - v.x + 1.0f, 0.0f) * fmaxf(v.w - v.y + 1.0f, 0.0f);
  }
  __syncthreads();
  int nv = nv_s;  // valid boxes occupy sorted positions [0, nv)
  if (tid < NPROP / 32) {  // init keep bitmask: 1 for p < nv
    int b0 = tid * 32;
    unsigned m = 0u;
    if (nv >= b0 + 32) m = ~0u;
    else if (nv > b0)  m = (1u << (nv - b0)) - 1u;
    keepbits[tid] = m;
  }
  __syncthreads();

  for (int base = 0; base < nv; base += CH) {
    int m = min(CH, nv - base);
    // ---- Phase 1: 32x32 bit matrix, 2 rows per wave via one ballot ----
    {
      int w   = tid >> 6;
      int ln  = tid & 63;
      int row = 2 * w + (ln >> 5);
      int col = ln & 31;
      int ri = base + (row < m ? row : 0);
      int cj = base + (col < m ? col : 0);
      float4 rb = bx[ri]; float ra = areas[ri];
      float4 cx = bx[cj]; float ca = areas[cj];
      bool bit = false;
      if (row < m && col < m && col > row) {
        float ix1 = fmaxf(rb.x, cx.x), iy1 = fmaxf(rb.y, cx.y);
        float ix2 = fminf(rb.z, cx.z), iy2 = fminf(rb.w, cx.w);
        float iw = fmaxf(ix2 - ix1 + 1.0f, 0.0f);
        float ih = fmaxf(iy2 - iy1 + 1.0f, 0.0f);
        float inter = iw * ih;
        float iou = inter / fmaxf(ra + ca - inter, 1e-6f);
        bit = iou > NMS_T;
      }
      unsigned long long bal = __ballot(bit);
      if (ln == 0) {
        rowmask[2 * w]     = (unsigned)(bal & 0xffffffffu);
        rowmask[2 * w + 1] = (unsigned)(bal >> 32);
      }
    }
    __syncthreads();
    // ---- Phase 2: single-thread unrolled greedy on bit rows (no shuffles in chain)
    if (tid < 64) {
      unsigned a = 0;
      if (tid == 0) {
        unsigned r[CH];
#pragma unroll
        for (int j = 0; j < CH; ++j) r[j] = rowmask[j];
        a = keepbits[base >> 5];
#pragma unroll
        for (int j = 0; j < CH; ++j)
          if (a & (1u << j)) a &= ~r[j];
        keepbits[base >> 5] = a;
        ccnt = __popc(a);
      }
      a = __shfl(a, 0);  // broadcast survivors to wave 0
      if (tid < CH && ((a >> tid) & 1u)) {   // compact survivor boxes
        int pos = __popc(a & ((1u << tid) - 1u));
        float4 v = bx[base + tid];
        cb[pos][0] = v.x; cb[pos][1] = v.y; cb[pos][2] = v.z; cb[pos][3] = v.w;
        cb[pos][4] = areas[base + tid];
      }
    }
    __syncthreads();
    // ---- Phase 3: chunk survivors suppress all later boxes, in parallel ----
    int cnt = ccnt;
    int lim = base + m;
    if (cnt > 0) {
      for (int p = lim + tid; p < nv; p += 1024) {
        unsigned kb = keepbits[p >> 5];
        if (!((kb >> (p & 31)) & 1u)) continue;
        float4 mb = bx[p];
        float  ar = areas[p];
        for (int q = 0; q < cnt; ++q) {
          float ix1 = fmaxf(mb.x, cb[q][0]), iy1 = fmaxf(mb.y, cb[q][1]);
          float ix2 = fminf(mb.z, cb[q][2]), iy2 = fminf(mb.w, cb[q][3]);
          float iw = fmaxf(ix2 - ix1 + 1.0f, 0.0f);
          float ih = fmaxf(iy2 - iy1 + 1.0f, 0.0f);
          float inter = iw * ih;
          float iou = inter / fmaxf(ar + cb[q][4] - inter, 1e-6f);
          if (iou > NMS_T) {
            atomicAnd(&keepbits[p >> 5], ~(1u << (p & 31)));
            break;
          }
        }
      }
    }
    __syncthreads();
  }

  for (int p = tid; p < NPROP; p += 1024)
    keepS[(side * NIMG + b) * NPROP + p] = (int)((keepbits[p >> 5] >> (p & 31)) & 1u);
}

// ---------------------------------------------------------------------------
// K3: per image: combine keeps, top-100 threshold via prefix scan, write output.
// grid = 4 blocks, 1024 threads (2 sorted positions per thread).
// ---------------------------------------------------------------------------
__global__ __launch_bounds__(1024) void finalize_kernel(
    const float* __restrict__ scores, const int* __restrict__ valid,
    const float* __restrict__ lbox, const float* __restrict__ rbox,
    const int* __restrict__ sidx, const int* __restrict__ keepS,
    float* __restrict__ out) {
  __shared__ int pc[1024];
  __shared__ float kth_s;
  int b = blockIdx.x;
  int tid = threadIdx.x;
  const int* si = sidx + b * NPROP;
  const int* kL = keepS + (0 * NIMG + b) * NPROP;
  const int* kR = keepS + (1 * NIMG + b) * NPROP;
  const float* sc = scores + b * NPROP;
  const int*   vd = valid  + b * NPROP;

  int p0 = tid * 2, p1 = p0 + 1;
  int o0 = si[p0], o1 = si[p1];
  int k0 = (kL[p0] && kR[p0] && vd[o0]) ? 1 : 0;
  int k1 = (kL[p1] && kR[p1] && vd[o1]) ? 1 : 0;
  if (tid == 0) kth_s = -INFINITY;
  pc[tid] = k0 + k1;
  __syncthreads();
  // Hillis-Steele inclusive scan over 1024 per-thread counts
  for (int ofs = 1; ofs < 1024; ofs <<= 1) {
    int add = (tid >= ofs) ? pc[tid - ofs] : 0;
    __syncthreads();
    pc[tid] += add;
    __syncthreads();
  }
  int incl  = pc[tid];
  int total = pc[1023];
  int ex    = incl - (k0 + k1);  // kept count before p0
  if (total >= DETS) {           // score of the 100th kept box (sorted desc)
    if (k0 && ex == DETS - 1)      kth_s = sc[o0];
    if (k1 && ex + k0 == DETS - 1) kth_s = sc[o1];
  }
  __syncthreads();
  float kth = kth_s;  // -inf if fewer than 100 kept -> keep all (ms >= -inf)

  float* ob = out + (size_t)b * NPROP * 9;
  for (int x = tid; x < NPROP * 9; x += 1024) ob[x] = 0.0f;
  __syncthreads();

#pragma unroll
  for (int q = 0; q < 2; ++q) {
    int kk = q ? k1 : k0;
    int oi = q ? o1 : o0;
    if (kk) {
      float s = sc[oi];
      if (s >= kth) {   // reproduces top_k tie semantics (ms >= kth)
        const float* L = lbox + (size_t)(b * NPROP + oi) * 4;
        const float* R = rbox + (size_t)(b * NPROP + oi) * 4;
        float* orow = ob + (size_t)oi * 9;
        orow[0] = L[0]; orow[1] = L[1]; orow[2] = L[2]; orow[3] = L[3];
        orow[4] = R[0]; orow[5] = R[1]; orow[6] = R[2]; orow[7] = R[3];
        orow[8] = s;
      }
    }
  }
}

// ---------------------------------------------------------------------------
extern "C" void kernel_launch(void* const* d_in, const int* in_sizes, int n_in,
                              void* d_out, int out_size, void* d_ws, size_t ws_size,
                              hipStream_t stream) {
  const float* logits = (const float*)d_in[0];   // [8192, 81]
  const float* reg    = (const float*)d_in[1];   // [8192, 648]
  const float* lprop  = (const float*)d_in[2];   // [8192, 4]
  const float* rprop  = (const float*)d_in[3];   // [8192, 4]
  float* out = (float*)d_out;                    // [4, 2048, 9]

  // workspace layout (float slots); total ~426 KB
  float* wsf    = (float*)d_ws;
  float* scores = wsf;                  // 8192
  int*   valid  = (int*)(wsf + 8192);   // 8192
  float* lbox   = wsf + 16384;          // 8192*4 (16B aligned)
  float* rbox   = wsf + 49152;          // 8192*4
  int*   sidx   = (int*)(wsf + 81920);  // 4*2048
  int*   keepS  = (int*)(wsf + 90112);  // 2*4*2048

  decode_kernel  <<<NIMG * NPROP / 4, 256,  0, stream>>>(logits, reg, lprop, rprop,
                                                         scores, valid, lbox, rbox);
  sort_nms_kernel<<<2 * NIMG,         1024, 0, stream>>>(scores, valid, lbox, rbox,
                                                         sidx, keepS);
  finalize_kernel<<<NIMG,             1024, 0, stream>>>(scores, valid, lbox, rbox,
                                                         sidx, keepS, out);
}

// Round 3
// 341.420 us; speedup vs baseline: 1.7867x; 1.3925x over previous
//
#include <hip/hip_runtime.h>
#include <math.h>

// Problem constants (B=4, N=2048, C=81)
#define NPROP 2048
#define NIMG 4
#define NCLS 81
#define REGW 648          // C*8
#define SCORE_THRESH 0.05f
#define NMS_T 0.5f
#define DETS 100
#define XC 1023.0f        // IMG_W - 1
#define YC 799.0f         // IMG_H - 1
#define BBOX_CLIP 4.135166556742356f  // log(1000/16)
#define CH 64             // NMS chunk size (u64 bitmask granularity)

// ---------------------------------------------------------------------------
// K1: per-row softmax-argmax + box decode (argmax class only) + clip.
// One wave (64 lanes) per row; 4 rows per 256-thread block.
// ---------------------------------------------------------------------------
__device__ __forceinline__ void decode_clip(float r0, float r1, float r2, float r3,
                                            float px1, float py1, float px2, float py2,
                                            float* __restrict__ o) {
  float w  = px2 - px1 + 1.0f;
  float h  = py2 - py1 + 1.0f;
  float cx = px1 + 0.5f * w;
  float cy = py1 + 0.5f * h;
  float dx = r0 / 10.0f;
  float dy = r1 / 10.0f;
  float dw = fminf(r2 / 5.0f, BBOX_CLIP);
  float dh = fminf(r3 / 5.0f, BBOX_CLIP);
  float pcx = dx * w + cx;
  float pcy = dy * h + cy;
  float pw = expf(dw) * w;
  float ph = expf(dh) * h;
  float x1 = pcx - 0.5f * pw;
  float y1 = pcy - 0.5f * ph;
  float x2 = pcx + 0.5f * pw - 1.0f;
  float y2 = pcy + 0.5f * ph - 1.0f;
  o[0] = fminf(fmaxf(x1, 0.0f), XC);
  o[1] = fminf(fmaxf(y1, 0.0f), YC);
  o[2] = fminf(fmaxf(x2, 0.0f), XC);
  o[3] = fminf(fmaxf(y2, 0.0f), YC);
}

__global__ __launch_bounds__(256) void decode_kernel(
    const float* __restrict__ logits, const float* __restrict__ reg,
    const float* __restrict__ lp, const float* __restrict__ rp,
    float* __restrict__ scores, int* __restrict__ valid,
    float* __restrict__ lbox, float* __restrict__ rbox) {
  int row  = blockIdx.x * 4 + (threadIdx.x >> 6);
  int lane = threadIdx.x & 63;
  const float* lr = logits + (size_t)row * NCLS;
  float a = lr[lane];                                       // classes 0..63
  float b = (lane < NCLS - 64) ? lr[lane + 64] : -INFINITY; // classes 64..80
  float v; int ci;
  if (b > a) { v = b; ci = lane + 64; } else { v = a; ci = lane; }
  // wave argmax (max value, min index on ties) == jnp.argmax semantics
  for (int o = 32; o; o >>= 1) {
    float ov = __shfl_xor(v, o);
    int   oc = __shfl_xor(ci, o);
    if (ov > v || (ov == v && oc < ci)) { v = ov; ci = oc; }
  }
  // sum of exp(x - max); softmax at argmax = 1/sum (numerator exp(0)==1)
  float e = expf(a - v) + ((lane < NCLS - 64) ? expf(b - v) : 0.0f);
  for (int o = 32; o; o >>= 1) e += __shfl_xor(e, o);
  if (lane == 0) {
    float score = 1.0f / e;
    scores[row] = score;
    valid[row]  = (ci >= 1 && score > SCORE_THRESH) ? 1 : 0;
    const float* r = reg + (size_t)row * REGW + ci * 8;
    const float* L = lp + row * 4;
    const float* R = rp + row * 4;
    decode_clip(r[0], r[1], r[2], r[3], L[0], L[1], L[2], L[3], lbox + (size_t)row * 4);
    decode_clip(r[4], r[5], r[6], r[7], R[0], R[1], R[2], R[3], rbox + (size_t)row * 4);
  }
}

// ---------------------------------------------------------------------------
// K2: per (image, side): bitonic sort, then 64-wide chunked greedy NMS.
// Phase 1: 64x64 IoU bit matrix via 4 ballots/wave (parallel).
// Phase 2: branchless 64-step scalar greedy on u64 rows (wave 0, redundant).
// Phase 3: fixed-trip, branchless survivor suppression (pipelineable loads).
// grid = 8 blocks (b = blk>>1, side = blk&1), 1024 threads.
// ---------------------------------------------------------------------------
__global__ __launch_bounds__(1024) void sort_nms_kernel(
    const float* __restrict__ scores, const int* __restrict__ valid,
    const float* __restrict__ lbox, const float* __restrict__ rbox,
    int* __restrict__ sidx, int* __restrict__ keepS) {
  __shared__ unsigned long long key[NPROP];        // 16 KB
  __shared__ float4 bx[NPROP];                     // 32 KB (sorted boxes)
  __shared__ float  areas[NPROP];                  // 8 KB
  __shared__ unsigned long long keepb[NPROP / 64]; // 256 B keep bitmask
  __shared__ unsigned long long rowm[CH];          // 512 B 64x64 bit matrix
  __shared__ float4 cb4[CH];                       // 1 KB survivor boxes
  __shared__ float  cba[CH];                       // 256 B survivor areas
  __shared__ int ccnt;
  __shared__ int nv_s;

  int b = blockIdx.x >> 1, side = blockIdx.x & 1;
  int tid = threadIdx.x;
  int ln  = tid & 63;
  const float* sc = scores + b * NPROP;
  const int*   vd = valid  + b * NPROP;
  const float4* boxes = (const float4*)(side == 0 ? lbox : rbox) + b * NPROP;

  if (tid == 0) nv_s = 0;
  __syncthreads();
  for (int p = tid; p < NPROP; p += 1024) {
    int vl = vd[p];
    float s = vl ? sc[p] : -INFINITY;
    unsigned u = __float_as_uint(s);
    u = (u & 0x80000000u) ? ~u : (u | 0x80000000u);   // total-order map
    key[p] = ((unsigned long long)(~u) << 32) | (unsigned)p; // asc == desc score, idx asc ties
    unsigned long long bal = __ballot(vl != 0);
    if (ln == 0) atomicAdd(&nv_s, __popcll(bal));
  }

  // bitonic ascending sort of 2048 u64 keys, 1024 comparators/stage
  for (int size = 2; size <= NPROP; size <<= 1) {
    for (int stride = size >> 1; stride; stride >>= 1) {
      __syncthreads();
      int i = ((tid & ~(stride - 1)) << 1) | (tid & (stride - 1));
      int j = i + stride;
      unsigned long long ka = key[i], kb = key[j];
      bool up = ((i & size) == 0);
      if ((ka > kb) == up) { key[i] = kb; key[j] = ka; }
    }
  }
  __syncthreads();

  for (int p = tid; p < NPROP; p += 1024) {
    int oi = (int)(key[p] & 0xffffffffu);
    if (side == 0) sidx[b * NPROP + p] = oi;   // both sides sort identically
    float4 v = boxes[oi];
    bx[p] = v;
    areas[p] = fmaxf(v.z - v.x + 1.0f, 0.0f) * fmaxf(v.w - v.y + 1.0f, 0.0f);
  }
  __syncthreads();
  int nv = nv_s;  // valid boxes occupy sorted positions [0, nv)
  if (tid < NPROP / 64) {  // init keep bitmask: 1 for p < nv
    int b0 = tid * 64;
    unsigned long long m = 0ull;
    if (nv >= b0 + 64) m = ~0ull;
    else if (nv > b0)  m = (1ull << (nv - b0)) - 1ull;
    keepb[tid] = m;
  }
  __syncthreads();

  for (int base = 0; base < nv; base += CH) {
    // ---- Phase 1: 64x64 upper-triangle IoU bit matrix, 4 ballots/wave ----
    {
      int w = tid >> 6;
      float4 cbox = bx[base + ln];
      float  care = areas[base + ln];
#pragma unroll
      for (int k = 0; k < 4; ++k) {
        int row = (k << 4) + w;
        float4 rbox = bx[base + row];     // wave-uniform -> LDS broadcast
        float  rare = areas[base + row];
        float ix1 = fmaxf(rbox.x, cbox.x), iy1 = fmaxf(rbox.y, cbox.y);
        float ix2 = fminf(rbox.z, cbox.z), iy2 = fminf(rbox.w, cbox.w);
        float iw = fmaxf(ix2 - ix1 + 1.0f, 0.0f);
        float ih = fmaxf(iy2 - iy1 + 1.0f, 0.0f);
        float inter = iw * ih;
        bool bit = (ln > row) && (inter > NMS_T * fmaxf(rare + care - inter, 1e-6f));
        unsigned long long bal = __ballot(bit);
        if (ln == 0) rowm[row] = bal;
      }
    }
    __syncthreads();
    // ---- Phase 2: branchless serial greedy on bit rows (wave 0, redundant) ----
    if (tid < 64) {
      unsigned long long a = keepb[base >> 6];
#pragma unroll
      for (int j = 0; j < CH; ++j)
        a &= ~((0ull - ((a >> j) & 1ull)) & rowm[j]);
      if (tid == 0) { keepb[base >> 6] = a; ccnt = __popcll(a); }
      if ((a >> tid) & 1ull) {    // compact survivors
        int pos = __popcll(a & ((1ull << tid) - 1ull));
        cb4[pos] = bx[base + tid];
        cba[pos] = areas[base + tid];
      }
    }
    __syncthreads();
    // ---- Phase 3: survivors suppress later boxes; fixed-trip, branchless ----
    int cnt = ccnt;
    if (cnt > 0) {
      for (int p = base + CH + tid; p < nv; p += 1024) {
        float4 mb = bx[p];
        float  ar = areas[p];
        bool sup = false;
#pragma unroll 4
        for (int q = 0; q < cnt; ++q) {
          float4 s = cb4[q];
          float ix1 = fmaxf(mb.x, s.x), iy1 = fmaxf(mb.y, s.y);
          float ix2 = fminf(mb.z, s.z), iy2 = fminf(mb.w, s.w);
          float iw = fmaxf(ix2 - ix1 + 1.0f, 0.0f);
          float ih = fmaxf(iy2 - iy1 + 1.0f, 0.0f);
          float inter = iw * ih;
          sup = sup | (inter > NMS_T * fmaxf(ar + cba[q] - inter, 1e-6f));
        }
        if (sup) atomicAnd(&keepb[p >> 6], ~(1ull << (p & 63)));
      }
    }
    // no trailing sync needed: phase 3 (keepb, cb4 reads) and next phase 1
    // (rowm writes) touch disjoint LDS; next phase-1 sync orders keepb reads.
  }
  __syncthreads();

  for (int p = tid; p < NPROP; p += 1024)
    keepS[(side * NIMG + b) * NPROP + p] = (int)((keepb[p >> 6] >> (p & 63)) & 1ull);
}

// ---------------------------------------------------------------------------
// K3: per image: combine keeps, top-100 threshold via prefix scan, write output.
// grid = 4 blocks, 1024 threads (2 sorted positions per thread).
// ---------------------------------------------------------------------------
__global__ __launch_bounds__(1024) void finalize_kernel(
    const float* __restrict__ scores, const int* __restrict__ valid,
    const float* __restrict__ lbox, const float* __restrict__ rbox,
    const int* __restrict__ sidx, const int* __restrict__ keepS,
    float* __restrict__ out) {
  __shared__ int pc[1024];
  __shared__ float kth_s;
  int b = blockIdx.x;
  int tid = threadIdx.x;
  const int* si = sidx + b * NPROP;
  const int* kL = keepS + (0 * NIMG + b) * NPROP;
  const int* kR = keepS + (1 * NIMG + b) * NPROP;
  const float* sc = scores + b * NPROP;
  const int*   vd = valid  + b * NPROP;

  int p0 = tid * 2, p1 = p0 + 1;
  int o0 = si[p0], o1 = si[p1];
  int k0 = (kL[p0] && kR[p0] && vd[o0]) ? 1 : 0;
  int k1 = (kL[p1] && kR[p1] && vd[o1]) ? 1 : 0;
  if (tid == 0) kth_s = -INFINITY;
  pc[tid] = k0 + k1;
  __syncthreads();
  // Hillis-Steele inclusive scan over 1024 per-thread counts
  for (int ofs = 1; ofs < 1024; ofs <<= 1) {
    int add = (tid >= ofs) ? pc[tid - ofs] : 0;
    __syncthreads();
    pc[tid] += add;
    __syncthreads();
  }
  int incl  = pc[tid];
  int total = pc[1023];
  int ex    = incl - (k0 + k1);  // kept count before p0
  if (total >= DETS) {           // score of the 100th kept box (sorted desc)
    if (k0 && ex == DETS - 1)      kth_s = sc[o0];
    if (k1 && ex + k0 == DETS - 1) kth_s = sc[o1];
  }
  __syncthreads();
  float kth = kth_s;  // -inf if fewer than 100 kept -> keep all (ms >= -inf)

  float* ob = out + (size_t)b * NPROP * 9;
  for (int x = tid; x < NPROP * 9; x += 1024) ob[x] = 0.0f;
  __syncthreads();

#pragma unroll
  for (int q = 0; q < 2; ++q) {
    int kk = q ? k1 : k0;
    int oi = q ? o1 : o0;
    if (kk) {
      float s = sc[oi];
      if (s >= kth) {   // reproduces top_k tie semantics (ms >= kth)
        const float* L = lbox + (size_t)(b * NPROP + oi) * 4;
        const float* R = rbox + (size_t)(b * NPROP + oi) * 4;
        float* orow = ob + (size_t)oi * 9;
        orow[0] = L[0]; orow[1] = L[1]; orow[2] = L[2]; orow[3] = L[3];
        orow[4] = R[0]; orow[5] = R[1]; orow[6] = R[2]; orow[7] = R[3];
        orow[8] = s;
      }
    }
  }
}

// ---------------------------------------------------------------------------
extern "C" void kernel_launch(void* const* d_in, const int* in_sizes, int n_in,
                              void* d_out, int out_size, void* d_ws, size_t ws_size,
                              hipStream_t stream) {
  const float* logits = (const float*)d_in[0];   // [8192, 81]
  const float* reg    = (const float*)d_in[1];   // [8192, 648]
  const float* lprop  = (const float*)d_in[2];   // [8192, 4]
  const float* rprop  = (const float*)d_in[3];   // [8192, 4]
  float* out = (float*)d_out;                    // [4, 2048, 9]

  // workspace layout (float slots); total ~426 KB
  float* wsf    = (float*)d_ws;
  float* scores = wsf;                  // 8192
  int*   valid  = (int*)(wsf + 8192);   // 8192
  float* lbox   = wsf + 16384;          // 8192*4 (16B aligned)
  float* rbox   = wsf + 49152;          // 8192*4
  int*   sidx   = (int*)(wsf + 81920);  // 4*2048
  int*   keepS  = (int*)(wsf + 90112);  // 2*4*2048

  decode_kernel  <<<NIMG * NPROP / 4, 256,  0, stream>>>(logits, reg, lprop, rprop,
                                                         scores, valid, lbox, rbox);
  sort_nms_kernel<<<2 * NIMG,         1024, 0, stream>>>(scores, valid, lbox, rbox,
                                                         sidx, keepS);
  finalize_kernel<<<NIMG,             1024, 0, stream>>>(scores, valid, lbox, rbox,
                                                         sidx, keepS, out);
}

// Round 4
// 148.520 us; speedup vs baseline: 4.1072x; 2.2988x over previous
//
#include <hip/hip_runtime.h>
#include <math.h>

// Problem constants (B=4, N=2048, C=81)
#define NPROP 2048
#define NIMG 4
#define NCLS 81
#define REGW 648          // C*8
#define SCORE_THRESH 0.05f
#define NMS_T 0.5f
#define DETS 100
#define XC 1023.0f        // IMG_W - 1
#define YC 799.0f         // IMG_H - 1
#define BBOX_CLIP 4.135166556742356f  // log(1000/16)
#define NBIN 4096         // 12-bit score-bin histogram
#define SEL 256           // target candidate count for tranche 1
#define MAXC 2176         // max candidate positions incl. alignment slack
#define KCAP 4096         // idx16 capacity (Cstart + P2 worst case ~3072)

// ---------------------------------------------------------------------------
// K1: per-row softmax-argmax + box decode (argmax class only) + clip.
// (unchanged from R1 — verified absmax 0)
// ---------------------------------------------------------------------------
__device__ __forceinline__ void decode_clip(float r0, float r1, float r2, float r3,
                                            float px1, float py1, float px2, float py2,
                                            float* __restrict__ o) {
  float w  = px2 - px1 + 1.0f;
  float h  = py2 - py1 + 1.0f;
  float cx = px1 + 0.5f * w;
  float cy = py1 + 0.5f * h;
  float dx = r0 / 10.0f;
  float dy = r1 / 10.0f;
  float dw = fminf(r2 / 5.0f, BBOX_CLIP);
  float dh = fminf(r3 / 5.0f, BBOX_CLIP);
  float pcx = dx * w + cx;
  float pcy = dy * h + cy;
  float pw = expf(dw) * w;
  float ph = expf(dh) * h;
  float x1 = pcx - 0.5f * pw;
  float y1 = pcy - 0.5f * ph;
  float x2 = pcx + 0.5f * pw - 1.0f;
  float y2 = pcy + 0.5f * ph - 1.0f;
  o[0] = fminf(fmaxf(x1, 0.0f), XC);
  o[1] = fminf(fmaxf(y1, 0.0f), YC);
  o[2] = fminf(fmaxf(x2, 0.0f), XC);
  o[3] = fminf(fmaxf(y2, 0.0f), YC);
}

__global__ __launch_bounds__(256) void decode_kernel(
    const float* __restrict__ logits, const float* __restrict__ reg,
    const float* __restrict__ lp, const float* __restrict__ rp,
    float* __restrict__ scores, int* __restrict__ valid,
    float* __restrict__ lbox, float* __restrict__ rbox) {
  int row  = blockIdx.x * 4 + (threadIdx.x >> 6);
  int lane = threadIdx.x & 63;
  const float* lr = logits + (size_t)row * NCLS;
  float a = lr[lane];
  float b = (lane < NCLS - 64) ? lr[lane + 64] : -INFINITY;
  float v; int ci;
  if (b > a) { v = b; ci = lane + 64; } else { v = a; ci = lane; }
  for (int o = 32; o; o >>= 1) {
    float ov = __shfl_xor(v, o);
    int   oc = __shfl_xor(ci, o);
    if (ov > v || (ov == v && oc < ci)) { v = ov; ci = oc; }
  }
  float e = expf(a - v) + ((lane < NCLS - 64) ? expf(b - v) : 0.0f);
  for (int o = 32; o; o >>= 1) e += __shfl_xor(e, o);
  if (lane == 0) {
    float score = 1.0f / e;
    scores[row] = score;
    valid[row]  = (ci >= 1 && score > SCORE_THRESH) ? 1 : 0;
    const float* r = reg + (size_t)row * REGW + ci * 8;
    const float* L = lp + row * 4;
    const float* R = rp + row * 4;
    decode_clip(r[0], r[1], r[2], r[3], L[0], L[1], L[2], L[3], lbox + (size_t)row * 4);
    decode_clip(r[4], r[5], r[6], r[7], R[0], R[1], R[2], R[3], rbox + (size_t)row * 4);
  }
}

// ---------------------------------------------------------------------------
// K2: per image (4 blocks, 1024 threads): histogram-select top candidates,
// bitonic-sort them, dual (L,R) chunked NMS with early stop at 100 AND-
// survivors, direct output write. Tranche 2 is a correctness fallback for
// <100 survivors among the selected prefix.
// ---------------------------------------------------------------------------
struct SNms {
  unsigned short idx16[KCAP];          // 8 KB  sorted candidate -> row idx
  unsigned int   v32[NPROP];           // 8 KB  flipped score bits per row (asc = desc score)
  int            hist[NBIN];           // 16 KB
  int            gsum[1024];           // 4 KB
  unsigned long long keepbL[MAXC/64];  // keep bitmasks (sorted positions)
  unsigned long long keepbR[MAXC/64];
  unsigned long long rowmL[64], rowmR[64];   // 64x64 chunk IoU bit matrices
  float4 cbL[64], cbR[64];             // chunk survivor boxes
  float  cbLa[64], cbRa[64];           // chunk survivor areas
  unsigned long long aL, aR;           // chunk keep masks (L, R)
  int cnt, prevCount, done, T, nv, ccL, ccR;
  unsigned int kthV;                   // v32 of the 100th AND-survivor
};                                      // ~41 KB total

__device__ __forceinline__ float areaf(float4 v) {
  return fmaxf(v.z - v.x + 1.0f, 0.0f) * fmaxf(v.w - v.y + 1.0f, 0.0f);
}
__device__ __forceinline__ bool iou_gt(float4 a, float aa, float4 b, float ba) {
  float ix1 = fmaxf(a.x, b.x), iy1 = fmaxf(a.y, b.y);
  float ix2 = fminf(a.z, b.z), iy2 = fminf(a.w, b.w);
  float iw = fmaxf(ix2 - ix1 + 1.0f, 0.0f);
  float ih = fmaxf(iy2 - iy1 + 1.0f, 0.0f);
  float inter = iw * ih;
  return inter > NMS_T * fmaxf(aa + ba - inter, 1e-6f);
}

__device__ void run_chunks(SNms* S, const float4* lboxG, const float4* rboxG,
                           const float* sc, float* ob,
                           int Cstart, int Cend, int CbEnd) {
  int tid = threadIdx.x, ln = tid & 63, w = tid >> 6;
  for (int base = Cstart; base < CbEnd; base += 64) {
    // ---- ph1: 64x64 IoU bit matrices; waves 0-7 build L, 8-15 build R ----
    {
      bool isR = (w >= 8);
      const float4* G = isR ? rboxG : lboxG;
      unsigned short ii = S->idx16[base + ln];
      int iiS = (ii == 0xFFFF) ? 0 : ii;       // pad-safe load
      float4 cbx = G[iiS];
      float  car = areaf(cbx);
      int w8 = w & 7;
#pragma unroll
      for (int k = 0; k < 8; ++k) {
        int row = w8 * 8 + k;
        unsigned short jj = S->idx16[base + row];
        int jjS = (jj == 0xFFFF) ? 0 : jj;
        float4 rbx = G[jjS];
        float  rar = areaf(rbx);
        bool bit = (ln > row) && iou_gt(rbx, rar, cbx, car);
        unsigned long long bal = __ballot(bit);
        if (ln == 0) { if (isR) S->rowmR[row] = bal; else S->rowmL[row] = bal; }
      }
    }
    __syncthreads();
    // ---- ph2: branchless serial greedy per side (waves 0 and 1) ----
    if (tid < 128) {
      bool isR = (tid >= 64);
      unsigned long long* km = isR ? S->keepbR : S->keepbL;
      unsigned long long* rm = isR ? S->rowmR  : S->rowmL;
      unsigned long long a = km[base >> 6];
#pragma unroll
      for (int j = 0; j < 64; ++j)
        a &= ~((0ull - ((a >> j) & 1ull)) & rm[j]);
      if (ln == 0) {
        km[base >> 6] = a;
        if (isR) { S->aR = a; S->ccR = __popcll(a); }
        else     { S->aL = a; S->ccL = __popcll(a); }
      }
      if ((a >> ln) & 1ull) {        // compact survivors for ph3
        int pos = __popcll(a & ((1ull << ln) - 1ull));
        unsigned short ii = S->idx16[base + ln];
        float4 v = (isR ? rboxG : lboxG)[ii];
        if (isR) { S->cbR[pos] = v; S->cbRa[pos] = areaf(v); }
        else     { S->cbL[pos] = v; S->cbLa[pos] = areaf(v); }
      }
    }
    __syncthreads();
    // ---- ph2b (wave 0): AND-survivors -> rank, kth, output rows ----
    if (w == 0) {
      unsigned long long m = S->aL & S->aR;
      int before = S->prevCount;
      bool bit = (m >> ln) & 1ull;
      int rank = before + (int)__popcll(m & ((1ull << ln) - 1ull));
      unsigned short ii = S->idx16[base + ln];
      int iiS = (ii == 0xFFFF) ? 0 : ii;
      unsigned vA = S->v32[iiS];
      unsigned long long selm = __ballot(bit && rank == DETS - 1);
      unsigned keffV = S->kthV;
      if (selm) {
        int l99 = __ffsll(selm) - 1;
        keffV = __shfl(vA, l99);
      }
      bool qual = bit && (rank < DETS || vA == keffV);  // top-100 or exact tie at kth
      if (qual) {
        float4 L = lboxG[ii], R = rboxG[ii];
        float s = sc[ii];
        float* orow = ob + (int)ii * 9;
        orow[0]=L.x; orow[1]=L.y; orow[2]=L.z; orow[3]=L.w;
        orow[4]=R.x; orow[5]=R.y; orow[6]=R.z; orow[7]=R.w;
        orow[8]=s;
      }
      if (ln == 0) {
        if (selm) S->kthV = keffV;
        S->prevCount = before + (int)__popcll(m);
      }
    } else {
      // ---- ph3 (waves 1-15): survivors suppress later candidates ----
      int cL = S->ccL, cR = S->ccR;
      for (int p = base + 64 + (tid - 64); p < CbEnd; p += 960) {
        unsigned short ii = S->idx16[p];
        if (ii == 0xFFFF) continue;
        float4 mbL = lboxG[ii]; float al = areaf(mbL);
        bool supL = false;
        for (int q = 0; q < cL; ++q)
          supL = supL || iou_gt(mbL, al, S->cbL[q], S->cbLa[q]);
        if (supL) atomicAnd(&S->keepbL[p >> 6], ~(1ull << (p & 63)));
        float4 mbR = rboxG[ii]; float ar_ = areaf(mbR);
        bool supR = false;
        for (int q = 0; q < cR; ++q)
          supR = supR || iou_gt(mbR, ar_, S->cbR[q], S->cbRa[q]);
        if (supR) atomicAnd(&S->keepbR[p >> 6], ~(1ull << (p & 63)));
      }
    }
    __syncthreads();
    // ---- stop check: 100 found and no exact tie continuing ----
    if (tid == 0 && S->prevCount >= DETS) {
      int nxt = base + 64;
      bool cont = false;
      if (nxt < Cend) {
        unsigned short ii = S->idx16[nxt];
        cont = (S->v32[ii] == S->kthV);   // exact score tie at kth
      }
      if (!cont) S->done = 1;
    }
    __syncthreads();
    if (S->done) break;
  }
}

__global__ __launch_bounds__(1024) void nms_out_kernel(
    const float* __restrict__ scores, const int* __restrict__ valid,
    const float* __restrict__ lbox, const float* __restrict__ rbox,
    float* __restrict__ out) {
  __shared__ SNms S;
  int b = blockIdx.x, tid = threadIdx.x, ln = tid & 63;
  const float* sc = scores + b * NPROP;
  const int*   vd = valid  + b * NPROP;
  const float4* lboxG = (const float4*)lbox + b * NPROP;
  const float4* rboxG = (const float4*)rbox + b * NPROP;
  float* ob = out + (size_t)b * NPROP * 9;

  // zero this image's output (2048*9 floats, float4-vectorized)
  float4* ob4 = (float4*)ob;
  float4 z4 = make_float4(0.f, 0.f, 0.f, 0.f);
  for (int i = tid; i < NPROP * 9 / 4; i += 1024) ob4[i] = z4;

  if (tid == 0) { S.cnt = 0; S.prevCount = 0; S.done = 0; S.T = NBIN - 1; S.kthV = 0u; S.nv = 0; }
  for (int i = tid; i < NBIN; i += 1024) S.hist[i] = 0;
  __syncthreads();

  // flipped score bits + 12-bit histogram (valid rows only)
  for (int p = tid; p < NPROP; p += 1024) {
    int vl = vd[p];
    unsigned v = 0xFFFFFFFFu;
    if (vl) {
      unsigned u = __float_as_uint(sc[p]);
      u = (u & 0x80000000u) ? ~u : (u | 0x80000000u);
      v = ~u;                                  // ascending v == descending score
      atomicAdd(&S.hist[v >> 20], 1);
    }
    S.v32[p] = v;
  }
  __syncthreads();

  // scan 4096 bins (4/thread) -> threshold bin T where cumulative >= SEL
  {
    int t = tid;
    int b0 = S.hist[4*t], b1 = S.hist[4*t+1], b2 = S.hist[4*t+2], b3 = S.hist[4*t+3];
    int s1 = b0 + b1, s2 = s1 + b2, s3 = s2 + b3;
    S.gsum[t] = s3;
    __syncthreads();
    for (int ofs = 1; ofs < 1024; ofs <<= 1) {
      int add = (t >= ofs) ? S.gsum[t - ofs] : 0;
      __syncthreads();
      S.gsum[t] += add;
      __syncthreads();
    }
    int off = S.gsum[t] - s3;
    int c0 = off + b0, c1 = off + s1, c2 = off + s2, c3 = off + s3;
    if      (c0 >= SEL && off < SEL) S.T = 4*t;
    else if (c1 >= SEL && c0  < SEL) S.T = 4*t+1;
    else if (c2 >= SEL && c1  < SEL) S.T = 4*t+2;
    else if (c3 >= SEL && c2  < SEL) S.T = 4*t+3;
    if (t == 1023) S.nv = S.gsum[1023];
  }
  __syncthreads();
  int T = S.T, nvTot = S.nv;

  int Cstart = 0, C1real = 0;
  for (int tr = 0; tr < 2; ++tr) {
    if (tr == 1 && (S.done || C1real >= nvTot)) break;  // fallback not needed
    // ---- compact this tranche's candidates into idx16[Cstart..) ----
    if (tid == 0) S.cnt = Cstart;
    __syncthreads();
    for (int p = tid; p < NPROP; p += 1024) {
      unsigned v = S.v32[p];
      bool cand = (v != 0xFFFFFFFFu) &&
                  (tr == 0 ? ((int)(v >> 20) <= T) : ((int)(v >> 20) > T));
      unsigned long long mb = __ballot(cand);
      int lpos = (int)__popcll(mb & ((1ull << ln) - 1ull));
      int wb = 0;
      if (ln == 0 && mb) wb = atomicAdd(&S.cnt, (int)__popcll(mb));
      wb = __shfl(wb, 0);
      if (cand) S.idx16[wb + lpos] = (unsigned short)p;
    }
    __syncthreads();
    int Cend = S.cnt;
    int C2 = Cend - Cstart;
    if (C2 > 0) {
      int P2 = 64;
      while (P2 < C2) P2 <<= 1;
      int CbEnd = Cstart + ((C2 + 63) & ~63);
      for (int p = Cend + tid; p < Cstart + P2; p += 1024) S.idx16[p] = 0xFFFF;
      __syncthreads();
      // ---- bitonic sort idx16[Cstart .. Cstart+P2) by (v32, idx) asc ----
      for (int size = 2; size <= P2; size <<= 1) {
        for (int stride = size >> 1; stride > 0; stride >>= 1) {
          __syncthreads();
          if (tid < (P2 >> 1)) {
            int il = ((tid & ~(stride - 1)) << 1) | (tid & (stride - 1));
            int i = Cstart + il, j = i + stride;
            unsigned short A = S.idx16[i], B = S.idx16[j];
            unsigned vA = (A == 0xFFFF) ? 0xFFFFFFFFu : S.v32[A];
            unsigned vB = (B == 0xFFFF) ? 0xFFFFFFFFu : S.v32[B];
            bool gt = (vA > vB) || (vA == vB && A > B);
            bool up = ((il & size) == 0);
            if (gt == up) { S.idx16[i] = B; S.idx16[j] = A; }
          }
        }
      }
      __syncthreads();
      // ---- init keep bits for this tranche's words ----
      for (int wd = (Cstart >> 6) + tid; wd < (CbEnd >> 6); wd += 1024) {
        int b0 = wd << 6;
        unsigned long long mfull = ~0ull;
        if (Cend < b0 + 64) mfull = (Cend > b0) ? ((1ull << (Cend - b0)) - 1ull) : 0ull;
        S.keepbL[wd] = mfull; S.keepbR[wd] = mfull;
      }
      __syncthreads();
      // ---- tranche 2 only: suppress new candidates by earlier survivors ----
      if (tr == 1) {
        for (int p = Cstart + tid; p < Cend; p += 1024) {
          unsigned short ii = S.idx16[p];
          float4 mbL = lboxG[ii]; float al  = areaf(mbL);
          float4 mbR = rboxG[ii]; float ar_ = areaf(mbR);
          bool supL = false, supR = false;
          for (int q = 0; q < C1real; ++q) {
            unsigned short jj = S.idx16[q];
            if ((S.keepbL[q >> 6] >> (q & 63)) & 1ull) {
              float4 t4 = lboxG[jj];
              supL = supL || iou_gt(mbL, al, t4, areaf(t4));
            }
            if ((S.keepbR[q >> 6] >> (q & 63)) & 1ull) {
              float4 t4 = rboxG[jj];
              supR = supR || iou_gt(mbR, ar_, t4, areaf(t4));
            }
          }
          if (supL) atomicAnd(&S.keepbL[p >> 6], ~(1ull << (p & 63)));
          if (supR) atomicAnd(&S.keepbR[p >> 6], ~(1ull << (p & 63)));
        }
        __syncthreads();
      }
      run_chunks(&S, lboxG, rboxG, sc, ob, Cstart, Cend, CbEnd);
      if (tr == 0) { C1real = Cend; Cstart = CbEnd; }
    } else if (tr == 0) {
      C1real = Cend;
    }
  }
}

// ---------------------------------------------------------------------------
extern "C" void kernel_launch(void* const* d_in, const int* in_sizes, int n_in,
                              void* d_out, int out_size, void* d_ws, size_t ws_size,
                              hipStream_t stream) {
  const float* logits = (const float*)d_in[0];   // [8192, 81]
  const float* reg    = (const float*)d_in[1];   // [8192, 648]
  const float* lprop  = (const float*)d_in[2];   // [8192, 4]
  const float* rprop  = (const float*)d_in[3];   // [8192, 4]
  float* out = (float*)d_out;                    // [4, 2048, 9]

  float* wsf    = (float*)d_ws;
  float* scores = wsf;                  // 8192
  int*   valid  = (int*)(wsf + 8192);   // 8192
  float* lbox   = wsf + 16384;          // 8192*4 (16B aligned)
  float* rbox   = wsf + 49152;          // 8192*4

  decode_kernel <<<NIMG * NPROP / 4, 256,  0, stream>>>(logits, reg, lprop, rprop,
                                                        scores, valid, lbox, rbox);
  nms_out_kernel<<<NIMG,             1024, 0, stream>>>(scores, valid, lbox, rbox, out);
}